// Round 1
// baseline (537.828 us; speedup 1.0000x reference)
//
#include <hip/hip_runtime.h>

// ---------------------------------------------------------------------------
// GNNQNetwork hetero-GAT, MI355X fp32. Round 5.
//
// R5 change: XCD-affinity for the two gather-bound edge passes.
//   Both passA and passB were fetching ~200MB/dispatch because every XCD
//   (blockIdx%8 round-robin) randomly gathered over ALL six edge types'
//   DR2/XR (resp. LS/LD/DR2) regions (~20MB) through its private 4MB L2:
//   8x replication + capacity misses, ~200GB/s/XCD L2-miss wall.
//   Now grid = 2048 (= 8 XCD x 32 CU x 8 blk/CU, fully co-resident) and
//   work is partitioned so each XCD touches 1-2 edge types whose gather
//   regions (mostly) fit its L2.
//   passB: et->XCD {0:[0,1] 1:[2] 2:[3] 3:[4,5] 4:[6] 5:[7]}
//          (et0/et3 share the 6.4MB XR-rv region -> 2 XCDs each).
//   passA: 8 equal 300k-edge chunks of the concatenated edge space.
//   Also: cnt tail items now use a wave-segmented scan (batch ids are
//   sorted => 64-way same-address ds_add was serializing).
// ---------------------------------------------------------------------------

constexpr int kNT = 100000, kNRV = 200000, kNR = 300000, kE = 400000;
constexpr int kTOTE = 6 * kE;      // 2,400,000 edges
constexpr int kSLOT = 1088;        // per-et P tile: 16x64 acc + 64 cnt
constexpr int kPSZ  = 6 * kSLOT;   // 6528
constexpr int kGRID = 2048;        // 8 XCDs x 256 co-resident blocks

// workspace offsets in 4-byte units (total 34.61 MB, proven footprint)
constexpr long long OFF_C    = 0;        // 6*2176: C rows + cb@2048
constexpr long long OFF_VS   = 13056;    // 6*20
constexpr long long OFF_VD   = 13176;    // 6*20
constexpr long long OFF_P    = 13296;    // kPSZ
constexpr long long OFF_XCAT = 19824;    // 64*512
constexpr long long OFF_LS   = 52592;    // 1.2M src logits (per-et bases)
constexpr long long OFF_LD   = 1252592;  // 1.2M dst logits (dense, drb bases)
constexpr long long OFF_PB   = 52592;    // aliases LS/LD after passA: 2048*1088 = 2.23M < 2.4M
constexpr long long OFF_W16  = 2452592;  // 2.4M halves (1.2M floats)
constexpr long long OFF_DR2  = 3652592;  // 1.2M float2 {denom, batch}
constexpr long long OFF_XR   = 6052592;  // 5.2M halves (2.6M floats)
// end 8652592 floats = 34.61 MB

// per-et constant tables
// src type: rv,t,r,rv,t,r ; dst type: t,rv,rv,r,r,t
__constant__ const int kLSB[6] = {0, 200000, 300000, 600000, 800000, 900000};
__constant__ const int kDRB[6] = {0, 100000, 300000, 500000, 800000, 1100000};
__constant__ const int kDLEN[6] = {100000, 200000, 200000, 300000, 300000, 100000};

// passB XCD affinity (dispatch rule: xcd = blockIdx % 8)
__constant__ const int kXCD2ET[8] = {0, 0, 1, 2, 3, 3, 4, 5};
__constant__ const int kXCDSUB[8] = {0, 1, 0, 0, 0, 1, 0, 0};
__constant__ const int kETNX[6]   = {2, 1, 1, 2, 1, 1};
__constant__ const int kETXCDA[6] = {0, 2, 3, 4, 6, 7};
__constant__ const int kETXCDB[6] = {1, 2, 3, 5, 6, 7};  // == A when kETNX==1

// ---------------------------------------------------------------------------
__global__ __launch_bounds__(256) void precompute_kernel(
    const float* encW_t, const float* encb_t,
    const float* encW_rv, const float* encb_rv,
    const float* encW_r, const float* encb_r,
    const float* W0, const float* as0, const float* ad0,
    const float* W1, const float* as1, const float* ad1,
    const float* W2, const float* as2, const float* ad2,
    const float* W3, const float* as3, const float* ad3,
    const float* W4, const float* as4, const float* ad4,
    const float* W5, const float* as5, const float* ad5,
    float* Cws, float* vsw, float* vdw)
{
  const float* encW[3] = {encW_t, encW_rv, encW_r};
  const float* encb[3] = {encb_t, encb_rv, encb_r};
  const int    Ks[3]   = {8, 13, 4};
  const float* Wv[6]  = {W0, W1, W2, W3, W4, W5};
  const float* asv[6] = {as0, as1, as2, as3, as4, as5};
  const float* adv[6] = {ad0, ad1, ad2, ad3, ad4, ad5};
  const int srcT[6] = {1, 0, 2, 1, 0, 2};
  const int dstT[6] = {0, 1, 1, 2, 2, 0};

  __shared__ float Cl[2176];
  __shared__ float wv[128];

  int et = blockIdx.x;
  int tid = threadIdx.x;
  int st = srcT[et], dt = dstT[et];
  const float* eW = encW[st];
  const float* eB = encb[st];
  int K = Ks[st];
  const float* W = Wv[et];
  const float* a_s = asv[et];
  const float* a_d = adv[et];
  float* Cslot = Cws + et * 2176;

  for (int idx = tid; idx < (K + 1) * 128; idx += 256) {
    int r = idx >> 7, j = idx & 127;
    const float* row = (r < K) ? (eW + r * 128) : eB;
    float acc = 0.f;
    for (int m = 0; m < 128; ++m) acc += row[m] * W[m * 128 + j];
    int o = (r < K) ? (r * 128 + j) : (2048 + j);
    Cl[o] = acc;
    Cslot[o] = acc;
  }
  if (tid < 128) {
    float acc = 0.f;
    for (int j = 0; j < 128; ++j) acc += W[tid * 128 + j] * a_d[j];
    wv[tid] = acc;
  }
  __syncthreads();
  if (tid <= K) {
    const float* row = (tid < K) ? (Cl + tid * 128) : (Cl + 2048);
    float acc = 0.f;
    for (int j = 0; j < 128; ++j) acc += row[j] * a_s[j];
    vsw[et * 20 + (tid < K ? tid : 16)] = acc;
  }
  int KD = Ks[dt];
  if (tid >= 32 && tid <= 32 + KD) {
    int k = tid - 32;
    const float* row = (k < KD) ? (encW[dt] + k * 128) : encb[dt];
    float acc = 0.f;
    for (int m = 0; m < 128; ++m) acc += row[m] * wv[m];
    vdw[et * 20 + (k < KD ? k : 16)] = acc;
  }
}

// ---------------------------------------------------------------------------
template <int K, int RH>
__device__ __forceinline__ void prep_one(
    const float* __restrict__ xr, float bf,
    const float* __restrict__ vsA, const float* __restrict__ vsB,
    const float* __restrict__ vdA, const float* __restrict__ vdB,
    float* lsA, float* lsB, float* ldA, float* ldB,
    float2* dr2A, float2* dr2B, _Float16* xrec)
{
  float a0 = 0.f, a1 = 0.f, a2 = 0.f, a3 = 0.f;
#pragma unroll
  for (int k = 0; k < K; ++k) {
    float xv = xr[k];
    a0 += xv * vsA[k]; a1 += xv * vsB[k];
    a2 += xv * vdA[k]; a3 += xv * vdB[k];
    xrec[k] = (_Float16)xv;
  }
#pragma unroll
  for (int k = K; k < RH; ++k) xrec[k] = (_Float16)0.f;
  *lsA = a0 + vsA[16];
  *lsB = a1 + vsB[16];
  *ldA = a2 + vdA[16];
  *ldB = a3 + vdB[16];
  *dr2A = make_float2(0.f, bf);
  *dr2B = make_float2(0.f, bf);
}

__global__ __launch_bounds__(256) void prep_kernel(
    const float* __restrict__ x_t, const float* __restrict__ x_rv,
    const float* __restrict__ x_r,
    const int* __restrict__ bt, const int* __restrict__ brv,
    const int* __restrict__ br,
    const float* __restrict__ vsw, const float* __restrict__ vdw,
    float* __restrict__ LS, float* __restrict__ LD,
    float2* __restrict__ DR2, _Float16* __restrict__ XR)
{
  int n = blockIdx.x * 256 + threadIdx.x;
  if (n >= kNT + kNRV + kNR) return;
  if (n < kNT) {
    // tile: src roles et1,et4 (K=8); dst roles et0,et5
    prep_one<8, 8>(x_t + n * 8, (float)bt[n],
                   vsw + 1 * 20, vsw + 4 * 20, vdw + 0 * 20, vdw + 5 * 20,
                   LS + 200000 + n, LS + 800000 + n,
                   LD + 0 + n, LD + 1100000 + n,
                   DR2 + 0 + n, DR2 + 1100000 + n,
                   XR + (long long)n * 8);
  } else if (n < kNT + kNRV) {
    int m = n - kNT;
    // rv: src roles et0,et3 (K=13); dst roles et1,et2
    prep_one<13, 16>(x_rv + m * 13, (float)brv[m],
                     vsw + 0 * 20, vsw + 3 * 20, vdw + 1 * 20, vdw + 2 * 20,
                     LS + 0 + m, LS + 600000 + m,
                     LD + 100000 + m, LD + 300000 + m,
                     DR2 + 100000 + m, DR2 + 300000 + m,
                     XR + 800000 + (long long)m * 16);
  } else {
    int m = n - kNT - kNRV;
    // road: src roles et2,et5 (K=4); dst roles et3,et4
    prep_one<4, 4>(x_r + m * 4, (float)br[m],
                   vsw + 2 * 20, vsw + 5 * 20, vdw + 3 * 20, vdw + 4 * 20,
                   LS + 300000 + m, LS + 900000 + m,
                   LD + 500000 + m, LD + 800000 + m,
                   DR2 + 500000 + m, DR2 + 800000 + m,
                   XR + 4000000 + (long long)m * 4);
  }
}

// ---------------------------------------------------------------------------
__device__ __forceinline__ void pickSD(
    int et,
    const int* s0, const int* s1, const int* s2,
    const int* s3, const int* s4, const int* s5,
    const int* d0, const int* d1, const int* d2,
    const int* d3, const int* d4, const int* d5,
    const int*& sp, const int*& dp)
{
  switch (et) {
    case 0: sp = s0; dp = d0; break;
    case 1: sp = s1; dp = d1; break;
    case 2: sp = s2; dp = d2; break;
    case 3: sp = s3; dp = d3; break;
    case 4: sp = s4; dp = d4; break;
    default: sp = s5; dp = d5; break;
  }
}

// passA: 8 equal 300k-edge chunks of the concatenated [0, 2.4M) edge space,
// chunk x pinned to XCD x (blockIdx%8). At most 2 ets per chunk; each loop
// below is et-uniform. Per-et gather regions (LS+LD+DR2 = 2-4.4MB) now live
// in the owning XCD's L2 instead of being replicated 8x.
__global__ __launch_bounds__(256, 8) void passA_kernel(
    const int* s0, const int* s1, const int* s2,
    const int* s3, const int* s4, const int* s5,
    const int* d0, const int* d1, const int* d2,
    const int* d3, const int* d4, const int* d5,
    const float* __restrict__ LS, const float* __restrict__ LD,
    float* __restrict__ DR2f, _Float16* __restrict__ W16)
{
  int xcd  = blockIdx.x & 7;
  int slot = blockIdx.x >> 3;           // 0..255
  int c0 = xcd * (kTOTE / 8);           // 300k-edge chunk
  int c1 = c0 + (kTOTE / 8);
  int etA = c0 / kE;
  int eA1 = (etA + 1) * kE;
  if (eA1 > c1) eA1 = c1;

  for (int half = 0; half < 2; ++half) {
    int et, rs, re;
    if (half == 0) {
      et = etA; rs = c0; re = eA1;
    } else {
      if (eA1 >= c1) break;
      et = etA + 1; rs = eA1; re = c1;
    }
    const int* sp; const int* dp;
    pickSD(et, s0, s1, s2, s3, s4, s5, d0, d1, d2, d3, d4, d5, sp, dp);
    int lsb = kLSB[et], drb = kDRB[et];
    int ebase = et * kE;
    for (int i = rs + slot * 256 + (int)threadIdx.x; i < re; i += 65536) {
      int e = i - ebase;
      int s = sp[e], d = dp[e];
      float t = LS[lsb + s] + LD[drb + d];
      t = t > 0.f ? t : 0.2f * t;
      _Float16 h = (_Float16)__expf(t);
      W16[i] = h;   // global layout et*kE + e == concatenated index i
      unsafeAtomicAdd(&DR2f[(long long)(drb + d) * 2], (float)h);
    }
  }
}

// ---------------------------------------------------------------------------
template <int K, int RH>
__device__ __forceinline__ void passB_loop(
    const int* __restrict__ sp, const int* __restrict__ dp,
    int drb, int dlen, long long xrb,
    const _Float16* __restrict__ W16et, const float2* __restrict__ DR2,
    const _Float16* __restrict__ XR, float* __restrict__ lp,
    int bIdx, int stride)
{
  int tid = threadIdx.x;
  int lane = tid & 63;

  // --- edges ---
  for (int i = bIdx * 256 + tid; i < kE; i += stride) {
    int s = sp[i], d = dp[i];
    float2 rec = DR2[drb + d];
    float w = (float)W16et[i];
    float alpha = w / fmaxf(rec.x, 1e-16f);
    int b = (int)rec.y;
    const _Float16* xp = XR + xrb + (long long)s * RH;
    float xv[K];
    if constexpr (RH == 4) {
      union { uint2 u; _Float16 h[4]; } U;
      U.u = *(const uint2*)xp;
#pragma unroll
      for (int k = 0; k < K; ++k) xv[k] = (float)U.h[k];
    } else if constexpr (RH == 8) {
      union { uint4 u; _Float16 h[8]; } U;
      U.u = *(const uint4*)xp;
#pragma unroll
      for (int k = 0; k < K; ++k) xv[k] = (float)U.h[k];
    } else {
      union { uint4 u[2]; _Float16 h[16]; } U;
      U.u[0] = *(const uint4*)xp;
      U.u[1] = *(const uint4*)(xp + 8);
#pragma unroll
      for (int k = 0; k < K; ++k) xv[k] = (float)U.h[k];
    }
    // LDS tile [k][64 b-slots]: bank = b%32 -> <=2-way, free
#pragma unroll
    for (int k = 0; k < K; ++k) atomicAdd(lp + k * 64 + b, alpha * xv[k]);
  }

  // --- cnt items: dst nodes with >=1 incoming edge, counted per batch ---
  // batch ids are sorted -> 64 consecutive records share a batch; a plain
  // per-lane ds_add would serialize 64-way same-address. Wave-segmented
  // scan -> one atomic per run.
  for (int base = bIdx * 256 + (tid & ~63); base < dlen; base += stride) {
    int j = base + lane;
    bool act = j < dlen;
    float2 rec = act ? DR2[drb + j] : make_float2(0.f, 0.f);
    int b = act ? (int)rec.y : (64 + lane);     // dummy: unique, run length 1
    int v = (act && rec.x > 0.f) ? 1 : 0;
#pragma unroll
    for (int d2 = 1; d2 < 64; d2 <<= 1) {
      int ob = __shfl_up(b, d2);
      int ov = __shfl_up(v, d2);
      if (lane >= d2 && ob == b) v += ov;
    }
    int bn = __shfl_down(b, 1);
    bool tailq = (lane == 63) || (bn != b);
    if (tailq && v > 0) atomicAdd(lp + 1024 + b, (float)v);
  }
}

__global__ __launch_bounds__(256, 8) void passB_kernel(
    const int* s0, const int* s1, const int* s2,
    const int* s3, const int* s4, const int* s5,
    const int* d0, const int* d1, const int* d2,
    const int* d3, const int* d4, const int* d5,
    const _Float16* __restrict__ W16, const float2* __restrict__ DR2,
    const _Float16* __restrict__ XR, float* __restrict__ PB)
{
  __shared__ float lp[kSLOT];
  for (int j = threadIdx.x; j < kSLOT; j += 256) lp[j] = 0.f;
  __syncthreads();
  int xcd  = blockIdx.x & 7;
  int slot = blockIdx.x >> 3;                 // 0..255
  int et = kXCD2ET[xcd];
  int nx = kETNX[et];
  int bIdx = slot * nx + kXCDSUB[xcd];        // block index within et
  int stride = 65536 * nx;                    // total threads working this et
  int drb = kDRB[et], dlen = kDLEN[et];
  const _Float16* W16et = W16 + (long long)et * kE;
  switch (et) {
    case 0: passB_loop<13,16>(s0, d0, drb, dlen, 800000,  W16et, DR2, XR, lp, bIdx, stride); break;
    case 1: passB_loop< 8, 8>(s1, d1, drb, dlen, 0,       W16et, DR2, XR, lp, bIdx, stride); break;
    case 2: passB_loop< 4, 4>(s2, d2, drb, dlen, 4000000, W16et, DR2, XR, lp, bIdx, stride); break;
    case 3: passB_loop<13,16>(s3, d3, drb, dlen, 800000,  W16et, DR2, XR, lp, bIdx, stride); break;
    case 4: passB_loop< 8, 8>(s4, d4, drb, dlen, 0,       W16et, DR2, XR, lp, bIdx, stride); break;
    default: passB_loop<4, 4>(s5, d5, drb, dlen, 4000000, W16et, DR2, XR, lp, bIdx, stride); break;
  }
  __syncthreads();
  float* dst = PB + (long long)blockIdx.x * kSLOT;
  for (int j = threadIdx.x; j < kSLOT; j += 256) dst[j] = lp[j];
}

// ---------------------------------------------------------------------------
// PB is indexed by raw passB blockIdx; et e's partials live at blocks
// {slot*8 + xcd : slot in [0,256), xcd in et's XCD set}.
__global__ __launch_bounds__(256) void reduceP_kernel(
    const float* __restrict__ PB, float* __restrict__ P)
{
  int j = blockIdx.x * 256 + threadIdx.x;
  if (j >= kPSZ) return;
  int et = j / kSLOT;
  int jj = j - et * kSLOT;
  float s = 0.f;
  {
    const float* base = PB + (long long)kETXCDA[et] * kSLOT + jj;
#pragma unroll 8
    for (int slot = 0; slot < 256; ++slot)
      s += base[(long long)slot * (8 * kSLOT)];
  }
  if (kETNX[et] == 2) {
    const float* base = PB + (long long)kETXCDB[et] * kSLOT + jj;
#pragma unroll 8
    for (int slot = 0; slot < 256; ++slot)
      s += base[(long long)slot * (8 * kSLOT)];
  }
  P[j] = s;
}

// ---------------------------------------------------------------------------
__device__ __forceinline__ int lowb(const int* a, int n, int v) {
  int lo = 0, hi = n;
  while (lo < hi) { int mid = (lo + hi) >> 1; if (a[mid] < v) lo = mid + 1; else hi = mid; }
  return lo;
}

__global__ __launch_bounds__(128) void finalize_kernel(
    const int* __restrict__ bt, const int* __restrict__ brv, const int* __restrict__ br,
    const float* __restrict__ xp,
    const float* __restrict__ fc1W, const float* __restrict__ fc1b,
    const float* __restrict__ fc2W, const float* __restrict__ fc2b,
    const float* __restrict__ b_rv2t, const float* __restrict__ b_r2t,
    const float* __restrict__ b_t2rv, const float* __restrict__ b_r2rv,
    const float* __restrict__ b_rv2r, const float* __restrict__ b_t2r,
    const float* __restrict__ Cws, const float* __restrict__ P,
    float* __restrict__ xcat)
{
  int b = blockIdx.x, tid = threadIdx.x;
  __shared__ float xps[64];
  __shared__ float p1s[128];
  __shared__ int cnts[3];
  if (tid < 64) xps[tid] = xp[b * 64 + tid];
  if (tid < 3) {
    const int* ba = (tid == 0) ? bt : (tid == 1 ? brv : br);
    int N = (tid == 0) ? kNT : (tid == 1 ? kNRV : kNR);
    cnts[tid] = lowb(ba, N, b + 1) - lowb(ba, N, b);
  }
  __syncthreads();
  float a = fc1b[tid];
  for (int k = 0; k < 64; ++k) a += xps[k] * fc1W[k * 128 + tid];
  p1s[tid] = fmaxf(a, 0.f);
  __syncthreads();
  float a2 = fc2b[tid];
  for (int k = 0; k < 128; ++k) a2 += p1s[k] * fc2W[k * 128 + tid];
  xcat[b * 512 + 384 + tid] = fmaxf(a2, 0.f);
  const int etA[3] = {0, 1, 3}, etB[3] = {5, 2, 4};
  const int KAv[3] = {13, 8, 13}, KBv[3] = {4, 4, 8};
  for (int t3 = 0; t3 < 3; ++t3) {
    int eA = etA[t3], eB = etB[t3];
    const float* CA = Cws + eA * 2176;
    const float* CB = Cws + eB * 2176;
    const float* pA = P + eA * kSLOT;   // [k*64 + b] layout
    const float* pB = P + eB * kSLOT;
    float cA = pA[1024 + b];
    float cB = pB[1024 + b];
    float v = cA * CA[2048 + tid] + cB * CB[2048 + tid];
    for (int k = 0; k < KAv[t3]; ++k) v += pA[k * 64 + b] * CA[k * 128 + tid];
    for (int k = 0; k < KBv[t3]; ++k) v += pB[k * 64 + b] * CB[k * 128 + tid];
    float cnt = (float)max(cnts[t3], 1);
    const float* bb1 = (t3 == 0) ? b_rv2t : (t3 == 1 ? b_t2rv : b_rv2r);
    const float* bb2 = (t3 == 0) ? b_r2t  : (t3 == 1 ? b_r2rv : b_t2r);
    xcat[b * 512 + t3 * 128 + tid] = v / cnt + bb1[tid] + bb2[tid];
  }
}

// ---------------------------------------------------------------------------
__global__ __launch_bounds__(256) void out_kernel(
    const float* __restrict__ xcat, const float* __restrict__ outW,
    const float* __restrict__ outb, float* __restrict__ out)
{
  int g = blockIdx.x * 256 + threadIdx.x;   // 64*512
  int r = g >> 9, c = g & 511;
  const float* xr = xcat + r * 512;
  float acc = outb[c];
  for (int k = 0; k < 512; ++k) acc += xr[k] * outW[k * 512 + c];
  out[g] = acc;
}

// ---------------------------------------------------------------------------
extern "C" void kernel_launch(void* const* d_in, const int* in_sizes, int n_in,
                              void* d_out, int out_size, void* d_ws, size_t ws_size,
                              hipStream_t stream) {
  const float* x_tile   = (const float*)d_in[0];
  const float* x_rv     = (const float*)d_in[1];
  const float* x_road   = (const float*)d_in[2];
  const float* x_player = (const float*)d_in[3];
  const float* enc_t_W  = (const float*)d_in[4];
  const float* enc_t_b  = (const float*)d_in[5];
  const float* enc_rv_W = (const float*)d_in[6];
  const float* enc_rv_b = (const float*)d_in[7];
  const float* enc_r_W  = (const float*)d_in[8];
  const float* enc_r_b  = (const float*)d_in[9];
  const float* W[6]; const float* As[6]; const float* Ad[6]; const float* Bb[6];
  for (int et = 0; et < 6; ++et) {
    W[et]  = (const float*)d_in[10 + 4 * et];
    As[et] = (const float*)d_in[11 + 4 * et];
    Ad[et] = (const float*)d_in[12 + 4 * et];
    Bb[et] = (const float*)d_in[13 + 4 * et];
  }
  const float* fc1W = (const float*)d_in[34];
  const float* fc1b = (const float*)d_in[35];
  const float* fc2W = (const float*)d_in[36];
  const float* fc2b = (const float*)d_in[37];
  const float* outW = (const float*)d_in[38];
  const float* outb = (const float*)d_in[39];
  const int* esrc[6]; const int* edst[6];
  for (int et = 0; et < 6; ++et) {
    esrc[et] = (const int*)d_in[40 + 2 * et];
    edst[et] = (const int*)d_in[41 + 2 * et];
  }
  const int* batch_t  = (const int*)d_in[52];
  const int* batch_rv = (const int*)d_in[53];
  const int* batch_r  = (const int*)d_in[54];

  float* wsF = (float*)d_ws;
  float* Cws  = wsF + OFF_C;
  float* vsw  = wsF + OFF_VS;
  float* vdw  = wsF + OFF_VD;
  float* P    = wsF + OFF_P;
  float* xcat = wsF + OFF_XCAT;
  float* LS   = wsF + OFF_LS;
  float* LD   = wsF + OFF_LD;
  float* PB   = wsF + OFF_PB;        // aliases LS/LD (dead after passA)
  _Float16* W16 = (_Float16*)(wsF + OFF_W16);
  float2* DR2 = (float2*)(wsF + OFF_DR2);
  float* DR2f = wsF + OFF_DR2;
  _Float16* XR = (_Float16*)(wsF + OFF_XR);
  float* out  = (float*)d_out;

  precompute_kernel<<<6, 256, 0, stream>>>(
      enc_t_W, enc_t_b, enc_rv_W, enc_rv_b, enc_r_W, enc_r_b,
      W[0], As[0], Ad[0], W[1], As[1], Ad[1], W[2], As[2], Ad[2],
      W[3], As[3], Ad[3], W[4], As[4], Ad[4], W[5], As[5], Ad[5],
      Cws, vsw, vdw);

  prep_kernel<<<(kNT + kNRV + kNR + 255) / 256, 256, 0, stream>>>(
      x_tile, x_rv, x_road, batch_t, batch_rv, batch_r, vsw, vdw,
      LS, LD, DR2, XR);

  passA_kernel<<<kGRID, 256, 0, stream>>>(
      esrc[0], esrc[1], esrc[2], esrc[3], esrc[4], esrc[5],
      edst[0], edst[1], edst[2], edst[3], edst[4], edst[5],
      LS, LD, DR2f, W16);

  passB_kernel<<<kGRID, 256, 0, stream>>>(
      esrc[0], esrc[1], esrc[2], esrc[3], esrc[4], esrc[5],
      edst[0], edst[1], edst[2], edst[3], edst[4], edst[5],
      W16, DR2, XR, PB);

  reduceP_kernel<<<(kPSZ + 255) / 256, 256, 0, stream>>>(PB, P);

  finalize_kernel<<<64, 128, 0, stream>>>(
      batch_t, batch_rv, batch_r, x_player,
      fc1W, fc1b, fc2W, fc2b,
      Bb[0], Bb[5], Bb[1], Bb[2], Bb[3], Bb[4],
      Cws, P, xcat);

  out_kernel<<<128, 256, 0, stream>>>(xcat, outW, outb, out);

  (void)in_sizes; (void)n_in; (void)out_size; (void)ws_size;
}

// Round 3
// 526.985 us; speedup vs baseline: 1.0206x; 1.0206x over previous
//
#include <hip/hip_runtime.h>

// ---------------------------------------------------------------------------
// GNNQNetwork hetero-GAT, MI355X fp32. Round 7.
//
// R7 = R6's data-layout gains WITHOUT the cooperative grid sync (R6 failed
// numerically, consistent with coop-launch/grid-sync not taking effect).
// Two plain edge kernels split at the softmax barrier (kernel boundary =
// proven coherence path from R0/R1):
//   - single-copy co-located src records: rv 64B {x13 f16, ls0, ls3},
//     t 32B {x8, ls1, ls4}, r 16B {x4, ls2, ls5}. Phase B re-derives w
//     from the SAME line that provides x -> no W16 buffer at all.
//   - dst record {ld|batch, denom} float2: batch id lives in the low 6
//     mantissa bits of ld (consistent in both phases; |dLd| ~ 2^-17 rel).
//     One 8B record serves phase-A load+atomic and phase-B alpha+batch.
//   - 5-deep explicit load batching in both edge kernels (12cy/line wall
//     in r0/r1 = outstanding-miss starvation; batch to fill MSHRs).
//   - P accumulated via 8 staged copies (P8[blk&7]) + tiny reduce.
// Random unique lines/edge: 2 (A) + 2 (B, mostly L2-warm) vs ~5 in R4.
// ---------------------------------------------------------------------------

constexpr int kNT = 100000, kNRV = 200000, kNR = 300000, kE = 400000;
constexpr int kSLOT = 1088;        // per-et P tile: 16x64 acc + 64 cnt
constexpr int kPSZ  = 6 * kSLOT;   // 6528
constexpr int kNBE  = 342;         // blocks per edge type
constexpr int kNTH  = kNBE * 256;  // 87552 threads per edge type
constexpr int kEPT  = 5;           // edge slots per thread (5*87552 >= 400k)

// workspace offsets in 4-byte units (total 30.8 MB < proven 34.61 MB)
constexpr long long OFF_C    = 0;        // 6*2176
constexpr long long OFF_VS   = 13056;    // 6*20
constexpr long long OFF_VD   = 13176;    // 6*20
constexpr long long OFF_P    = 13296;    // 6*1088
constexpr long long OFF_XCAT = 19824;    // 64*512
constexpr long long OFF_SRV  = 52592;    // rv recs: 200k * 16 floats (64B)
constexpr long long OFF_ST   = 3252592;  // t recs: 100k * 8 floats (32B)
constexpr long long OFF_SR   = 4052592;  // r recs: 300k * 4 floats (16B)
constexpr long long OFF_LDD  = 5252592;  // dst recs {ld|b, denom}: 1.2M*8B
constexpr long long OFF_P8   = 7652592;  // 8 staged P copies: 8*6528
// end 7704816 floats = 30.8 MB

// per-et tables. src type: rv,t,r,rv,t,r ; dst type: t,rv,rv,r,r,t
__constant__ const int kDRB[6]   = {0, 100000, 300000, 500000, 800000, 1100000};
__constant__ const int kDLEN[6]  = {100000, 200000, 200000, 300000, 300000, 100000};
__constant__ const int kLSOFF[6] = {7, 4, 2, 8, 5, 3};   // ls word within src rec
__constant__ const int kRSZ[6]   = {16, 8, 4, 16, 8, 4}; // src rec size in words

// ---------------------------------------------------------------------------
__device__ __forceinline__ int lowb(const int* a, int n, int v) {
  int lo = 0, hi = n;
  while (lo < hi) { int mid = (lo + hi) >> 1; if (a[mid] < v) lo = mid + 1; else hi = mid; }
  return lo;
}

static __device__ __forceinline__ unsigned p2h(float a, float b) {
  _Float16 ha = (_Float16)a, hb = (_Float16)b;
  unsigned short ua = __builtin_bit_cast(unsigned short, ha);
  unsigned short ub = __builtin_bit_cast(unsigned short, hb);
  return (unsigned)ua | ((unsigned)ub << 16);
}

// embed batch id (0..63) into low 6 mantissa bits of ld
static __device__ __forceinline__ float emb(float ld, int b) {
  return __uint_as_float((__float_as_uint(ld) & ~63u) | (unsigned)b);
}

// ---------------------------------------------------------------------------
__global__ __launch_bounds__(256) void precompute_kernel(
    const float* encW_t, const float* encb_t,
    const float* encW_rv, const float* encb_rv,
    const float* encW_r, const float* encb_r,
    const float* W0, const float* as0, const float* ad0,
    const float* W1, const float* as1, const float* ad1,
    const float* W2, const float* as2, const float* ad2,
    const float* W3, const float* as3, const float* ad3,
    const float* W4, const float* as4, const float* ad4,
    const float* W5, const float* as5, const float* ad5,
    float* Cws, float* vsw, float* vdw, float* P8)
{
  const float* encW[3] = {encW_t, encW_rv, encW_r};
  const float* encb[3] = {encb_t, encb_rv, encb_r};
  const int    Ks[3]   = {8, 13, 4};
  const float* Wv[6]  = {W0, W1, W2, W3, W4, W5};
  const float* asv[6] = {as0, as1, as2, as3, as4, as5};
  const float* adv[6] = {ad0, ad1, ad2, ad3, ad4, ad5};
  const int srcT[6] = {1, 0, 2, 1, 0, 2};
  const int dstT[6] = {0, 1, 1, 2, 2, 0};

  __shared__ float Cl[2176];
  __shared__ float wv[128];

  int et = blockIdx.x;
  int tid = threadIdx.x;
  int st = srcT[et], dt = dstT[et];
  const float* eW = encW[st];
  const float* eB = encb[st];
  int K = Ks[st];
  const float* W = Wv[et];
  const float* a_s = asv[et];
  const float* a_d = adv[et];
  float* Cslot = Cws + et * 2176;

  // zero this et's slab in all 8 staged P copies
  for (int c = 0; c < 8; ++c)
    for (int i = tid; i < kSLOT; i += 256)
      P8[c * kPSZ + et * kSLOT + i] = 0.f;

  for (int idx = tid; idx < (K + 1) * 128; idx += 256) {
    int r = idx >> 7, j = idx & 127;
    const float* row = (r < K) ? (eW + r * 128) : eB;
    float acc = 0.f;
    for (int m = 0; m < 128; ++m) acc += row[m] * W[m * 128 + j];
    int o = (r < K) ? (r * 128 + j) : (2048 + j);
    Cl[o] = acc;
    Cslot[o] = acc;
  }
  if (tid < 128) {
    float acc = 0.f;
    for (int j = 0; j < 128; ++j) acc += W[tid * 128 + j] * a_d[j];
    wv[tid] = acc;
  }
  __syncthreads();
  if (tid <= K) {
    const float* row = (tid < K) ? (Cl + tid * 128) : (Cl + 2048);
    float acc = 0.f;
    for (int j = 0; j < 128; ++j) acc += row[j] * a_s[j];
    vsw[et * 20 + (tid < K ? tid : 16)] = acc;
  }
  int KD = Ks[dt];
  if (tid >= 32 && tid <= 32 + KD) {
    int k = tid - 32;
    const float* row = (k < KD) ? (encW[dt] + k * 128) : encb[dt];
    float acc = 0.f;
    for (int m = 0; m < 128; ++m) acc += row[m] * wv[m];
    vdw[et * 20 + (k < KD ? k : 16)] = acc;
  }
}

// ---------------------------------------------------------------------------
__global__ __launch_bounds__(256) void prep_kernel(
    const float* __restrict__ x_t, const float* __restrict__ x_rv,
    const float* __restrict__ x_r,
    const int* __restrict__ bt, const int* __restrict__ brv,
    const int* __restrict__ br,
    const float* __restrict__ vsw, const float* __restrict__ vdw,
    uint4* __restrict__ SRVq, uint4* __restrict__ STq, uint4* __restrict__ SRq,
    float* __restrict__ LDDf)
{
  int n = blockIdx.x * 256 + threadIdx.x;
  if (n >= kNT + kNRV + kNR) return;
  if (n < kNT) {
    // tile: src roles et1,et4 (K=8); dst roles et0,et5
    const float* xr = x_t + n * 8;
    int b = bt[n];
    const float* vsA = vsw + 1 * 20, *vsB = vsw + 4 * 20;
    const float* vdA = vdw + 0 * 20, *vdB = vdw + 5 * 20;
    float x[8]; float a0 = 0, a1 = 0, a2 = 0, a3 = 0;
#pragma unroll
    for (int k = 0; k < 8; ++k) {
      x[k] = xr[k];
      a0 += x[k] * vsA[k]; a1 += x[k] * vsB[k];
      a2 += x[k] * vdA[k]; a3 += x[k] * vdB[k];
    }
    float ls1 = a0 + vsA[16], ls4 = a1 + vsB[16];
    float ld0 = a2 + vdA[16], ld5 = a3 + vdB[16];
    STq[(long long)n * 2] =
        make_uint4(p2h(x[0], x[1]), p2h(x[2], x[3]), p2h(x[4], x[5]), p2h(x[6], x[7]));
    STq[(long long)n * 2 + 1] =
        make_uint4(__float_as_uint(ls1), __float_as_uint(ls4), 0, 0);
    LDDf[(long long)n * 2] = emb(ld0, b);
    LDDf[(long long)n * 2 + 1] = 0.f;
    LDDf[(long long)(1100000 + n) * 2] = emb(ld5, b);
    LDDf[(long long)(1100000 + n) * 2 + 1] = 0.f;
  } else if (n < kNT + kNRV) {
    int m = n - kNT;
    // rv: src roles et0,et3 (K=13); dst roles et1,et2
    const float* xr = x_rv + m * 13;
    int b = brv[m];
    const float* vsA = vsw + 0 * 20, *vsB = vsw + 3 * 20;
    const float* vdA = vdw + 1 * 20, *vdB = vdw + 2 * 20;
    float x[13]; float a0 = 0, a1 = 0, a2 = 0, a3 = 0;
#pragma unroll
    for (int k = 0; k < 13; ++k) {
      x[k] = xr[k];
      a0 += x[k] * vsA[k]; a1 += x[k] * vsB[k];
      a2 += x[k] * vdA[k]; a3 += x[k] * vdB[k];
    }
    float ls0 = a0 + vsA[16], ls3 = a1 + vsB[16];
    float ld1 = a2 + vdA[16], ld2 = a3 + vdB[16];
    SRVq[(long long)m * 4] =
        make_uint4(p2h(x[0], x[1]), p2h(x[2], x[3]), p2h(x[4], x[5]), p2h(x[6], x[7]));
    SRVq[(long long)m * 4 + 1] =
        make_uint4(p2h(x[8], x[9]), p2h(x[10], x[11]), p2h(x[12], 0.f),
                   __float_as_uint(ls0));
    SRVq[(long long)m * 4 + 2] = make_uint4(__float_as_uint(ls3), 0, 0, 0);
    LDDf[(long long)(100000 + m) * 2] = emb(ld1, b);
    LDDf[(long long)(100000 + m) * 2 + 1] = 0.f;
    LDDf[(long long)(300000 + m) * 2] = emb(ld2, b);
    LDDf[(long long)(300000 + m) * 2 + 1] = 0.f;
  } else {
    int m = n - kNT - kNRV;
    // road: src roles et2,et5 (K=4); dst roles et3,et4
    const float* xr = x_r + m * 4;
    int b = br[m];
    const float* vsA = vsw + 2 * 20, *vsB = vsw + 5 * 20;
    const float* vdA = vdw + 3 * 20, *vdB = vdw + 4 * 20;
    float x[4]; float a0 = 0, a1 = 0, a2 = 0, a3 = 0;
#pragma unroll
    for (int k = 0; k < 4; ++k) {
      x[k] = xr[k];
      a0 += x[k] * vsA[k]; a1 += x[k] * vsB[k];
      a2 += x[k] * vdA[k]; a3 += x[k] * vdB[k];
    }
    float ls2 = a0 + vsA[16], ls5 = a1 + vsB[16];
    float ld3 = a2 + vdA[16], ld4 = a3 + vdB[16];
    SRq[m] = make_uint4(p2h(x[0], x[1]), p2h(x[2], x[3]),
                        __float_as_uint(ls2), __float_as_uint(ls5));
    LDDf[(long long)(500000 + m) * 2] = emb(ld3, b);
    LDDf[(long long)(500000 + m) * 2 + 1] = 0.f;
    LDDf[(long long)(800000 + m) * 2] = emb(ld4, b);
    LDDf[(long long)(800000 + m) * 2 + 1] = 0.f;
  }
}

// ---------------------------------------------------------------------------
__device__ __forceinline__ void pickSD(
    int et,
    const int* s0, const int* s1, const int* s2,
    const int* s3, const int* s4, const int* s5,
    const int* d0, const int* d1, const int* d2,
    const int* d3, const int* d4, const int* d5,
    const int*& sp, const int*& dp)
{
  switch (et) {
    case 0: sp = s0; dp = d0; break;
    case 1: sp = s1; dp = d1; break;
    case 2: sp = s2; dp = d2; break;
    case 3: sp = s3; dp = d3; break;
    case 4: sp = s4; dp = d4; break;
    default: sp = s5; dp = d5; break;
  }
}

// ---------------------------------------------------------------------------
// edgeA: w = exp(leaky(ls+ld)); denom += w. 5-deep batched gathers.
__global__ __launch_bounds__(256, 8) void edgeA_kernel(
    const int* s0, const int* s1, const int* s2,
    const int* s3, const int* s4, const int* s5,
    const int* d0, const int* d1, const int* d2,
    const int* d3, const int* d4, const int* d5,
    const unsigned* __restrict__ SRVu, const unsigned* __restrict__ STu,
    const unsigned* __restrict__ SRu, float* __restrict__ LDDf)
{
  int et = blockIdx.x / kNBE;
  int bIdx = blockIdx.x - et * kNBE;
  const int* sp; const int* dp;
  pickSD(et, s0, s1, s2, s3, s4, s5, d0, d1, d2, d3, d4, d5, sp, dp);
  const unsigned* su = (et == 1 || et == 4) ? STu : ((et == 2 || et == 5) ? SRu : SRVu);
  const int rsz = kRSZ[et];
  const int lso = kLSOFF[et];
  const int drb = kDRB[et];
  int base = bIdx * 256 + (int)threadIdx.x;

  int s[kEPT], d[kEPT]; bool ok[kEPT];
#pragma unroll
  for (int j = 0; j < kEPT; ++j) {
    int e = base + j * kNTH;
    ok[j] = e < kE;
    int ee = ok[j] ? e : 0;
    s[j] = sp[ee]; d[j] = dp[ee];
  }
  float ls[kEPT];
#pragma unroll
  for (int j = 0; j < kEPT; ++j)
    ls[j] = __uint_as_float(su[(long long)s[j] * rsz + lso]);
  float ld[kEPT];
#pragma unroll
  for (int j = 0; j < kEPT; ++j)
    ld[j] = LDDf[(long long)(drb + d[j]) * 2];
#pragma unroll
  for (int j = 0; j < kEPT; ++j) {
    float t = ls[j] + ld[j];
    t = t > 0.f ? t : 0.2f * t;
    float w = __expf(t);
    if (ok[j]) unsafeAtomicAdd(&LDDf[(long long)(drb + d[j]) * 2 + 1], w);
  }
}

// ---------------------------------------------------------------------------
// edgeB: recompute w from the same record lines, alpha = w/denom,
// accumulate alpha*x into LDS [k][64 batches], then cnt, then dump to P8.
// TYPE: 0=t(K=8), 1=rv(K=13), 2=r(K=4). RSEL selects the role's ls slot.
template <int TYPE, int RSEL>
__device__ __forceinline__ void ebflow(
    int bIdx,
    const int* __restrict__ sp, const int* __restrict__ dp,
    const uint4* __restrict__ srq, const float2* __restrict__ LDD2,
    int drb, int dlen, float* lp)
{
  constexpr int K = (TYPE == 0) ? 8 : ((TYPE == 1) ? 13 : 4);
  const int tid = threadIdx.x;
  const int lane = tid & 63;
  int base = bIdx * 256 + tid;

  int s[kEPT], d[kEPT]; bool ok[kEPT];
#pragma unroll
  for (int j = 0; j < kEPT; ++j) {
    int e = base + j * kNTH;
    ok[j] = e < kE;
    int ee = ok[j] ? e : 0;
    s[j] = sp[ee]; d[j] = dp[ee];
  }
  uint4 q0[kEPT], q1[kEPT];
  float lsx[kEPT];
#pragma unroll
  for (int j = 0; j < kEPT; ++j) {
    if (TYPE == 0) {
      q0[j] = srq[(long long)s[j] * 2];
      lsx[j] = __uint_as_float(
          ((const unsigned*)srq)[(long long)s[j] * 8 + (RSEL ? 5 : 4)]);
    } else if (TYPE == 1) {
      q0[j] = srq[(long long)s[j] * 4];
      q1[j] = srq[(long long)s[j] * 4 + 1];
      lsx[j] = RSEL
          ? __uint_as_float(((const unsigned*)srq)[(long long)s[j] * 16 + 8])
          : __uint_as_float(q1[j].w);
    } else {
      q0[j] = srq[s[j]];
      lsx[j] = __uint_as_float(RSEL ? q0[j].w : q0[j].z);
    }
  }
  float2 f2[kEPT];
#pragma unroll
  for (int j = 0; j < kEPT; ++j) f2[j] = LDD2[drb + d[j]];

#pragma unroll
  for (int j = 0; j < kEPT; ++j) {
    if (!ok[j]) continue;
    int b = (int)(__float_as_uint(f2[j].x) & 63u);
    float t = lsx[j] + f2[j].x;       // same bits as edgeA -> same w
    t = t > 0.f ? t : 0.2f * t;
    float w = __expf(t);
    float alpha = w / fmaxf(f2[j].y, 1e-16f);
    float xv[K];
    if (TYPE == 0) {
      const _Float16* h = (const _Float16*)&q0[j];
#pragma unroll
      for (int k = 0; k < 8; ++k) xv[k] = (float)h[k];
    } else if (TYPE == 1) {
      const _Float16* h = (const _Float16*)&q0[j];
#pragma unroll
      for (int k = 0; k < 8; ++k) xv[k] = (float)h[k];
      const _Float16* h2 = (const _Float16*)&q1[j];
#pragma unroll
      for (int k = 0; k < 5; ++k) xv[8 + k] = (float)h2[k];
    } else {
      const _Float16* h = (const _Float16*)&q0[j];
#pragma unroll
      for (int k = 0; k < 4; ++k) xv[k] = (float)h[k];
    }
#pragma unroll
    for (int k = 0; k < K; ++k) atomicAdd(lp + k * 64 + b, alpha * xv[k]);
  }

  // cnt: dst nodes with >=1 edge, per batch (wave-segmented scan; batch ids
  // sorted so runs are long -> one LDS atomic per run).
  for (int base2 = bIdx * 256 + (tid & ~63); base2 < dlen; base2 += kNTH) {
    int j2 = base2 + lane;
    bool a2 = j2 < dlen;
    float2 r2 = a2 ? LDD2[drb + j2] : make_float2(0.f, 0.f);
    int b2 = a2 ? (int)(__float_as_uint(r2.x) & 63u) : (64 + lane);
    int v = (a2 && r2.y > 0.f) ? 1 : 0;
#pragma unroll
    for (int d2 = 1; d2 < 64; d2 <<= 1) {
      int ob = __shfl_up(b2, d2);
      int ov = __shfl_up(v, d2);
      if (lane >= d2 && ob == b2) v += ov;
    }
    int bn = __shfl_down(b2, 1);
    if (((lane == 63) || (bn != b2)) && v > 0) atomicAdd(lp + 1024 + b2, (float)v);
  }
}

__global__ __launch_bounds__(256, 4) void edgeB_kernel(
    const int* s0, const int* s1, const int* s2,
    const int* s3, const int* s4, const int* s5,
    const int* d0, const int* d1, const int* d2,
    const int* d3, const int* d4, const int* d5,
    const uint4* SRVq, const uint4* STq, const uint4* SRq,
    const float2* __restrict__ LDD2, float* __restrict__ P8)
{
  __shared__ float lp[kSLOT];
  for (int j = threadIdx.x; j < kSLOT; j += 256) lp[j] = 0.f;
  __syncthreads();
  int et = blockIdx.x / kNBE;
  int bIdx = blockIdx.x - et * kNBE;
  constexpr int KK[6] = {13, 8, 4, 13, 8, 4};
  switch (et) {
    case 0: ebflow<1, 0>(bIdx, s0, d0, SRVq, LDD2, 0,       100000, lp); break;
    case 1: ebflow<0, 0>(bIdx, s1, d1, STq,  LDD2, 100000,  200000, lp); break;
    case 2: ebflow<2, 0>(bIdx, s2, d2, SRq,  LDD2, 300000,  200000, lp); break;
    case 3: ebflow<1, 1>(bIdx, s3, d3, SRVq, LDD2, 500000,  300000, lp); break;
    case 4: ebflow<0, 1>(bIdx, s4, d4, STq,  LDD2, 800000,  300000, lp); break;
    default: ebflow<2, 1>(bIdx, s5, d5, SRq, LDD2, 1100000, 100000, lp); break;
  }
  __syncthreads();
  int K = KK[et];
  float* slab = P8 + (long long)(blockIdx.x & 7) * kPSZ + (long long)et * kSLOT;
  for (int i = threadIdx.x; i < kSLOT; i += 256) {
    if (i >= K * 64 && i < 1024) continue;
    float v = lp[i];
    if (v != 0.f) unsafeAtomicAdd(&slab[i], v);
  }
}

// ---------------------------------------------------------------------------
__global__ __launch_bounds__(256) void reduceP8_kernel(
    const float* __restrict__ P8, float* __restrict__ P)
{
  int j = blockIdx.x * 256 + threadIdx.x;
  if (j >= kPSZ) return;
  float s = 0.f;
#pragma unroll
  for (int c = 0; c < 8; ++c) s += P8[c * kPSZ + j];
  P[j] = s;
}

// ---------------------------------------------------------------------------
__global__ __launch_bounds__(128) void finalize_kernel(
    const int* __restrict__ bt, const int* __restrict__ brv, const int* __restrict__ br,
    const float* __restrict__ xp,
    const float* __restrict__ fc1W, const float* __restrict__ fc1b,
    const float* __restrict__ fc2W, const float* __restrict__ fc2b,
    const float* __restrict__ b_rv2t, const float* __restrict__ b_r2t,
    const float* __restrict__ b_t2rv, const float* __restrict__ b_r2rv,
    const float* __restrict__ b_rv2r, const float* __restrict__ b_t2r,
    const float* __restrict__ Cws, const float* __restrict__ P,
    float* __restrict__ xcat)
{
  int b = blockIdx.x, tid = threadIdx.x;
  __shared__ float xps[64];
  __shared__ float p1s[128];
  __shared__ int cnts[3];
  if (tid < 64) xps[tid] = xp[b * 64 + tid];
  if (tid < 3) {
    const int* ba = (tid == 0) ? bt : (tid == 1 ? brv : br);
    int N = (tid == 0) ? kNT : (tid == 1 ? kNRV : kNR);
    cnts[tid] = lowb(ba, N, b + 1) - lowb(ba, N, b);
  }
  __syncthreads();
  float a = fc1b[tid];
  for (int k = 0; k < 64; ++k) a += xps[k] * fc1W[k * 128 + tid];
  p1s[tid] = fmaxf(a, 0.f);
  __syncthreads();
  float a2 = fc2b[tid];
  for (int k = 0; k < 128; ++k) a2 += p1s[k] * fc2W[k * 128 + tid];
  xcat[b * 512 + 384 + tid] = fmaxf(a2, 0.f);
  const int etA[3] = {0, 1, 3}, etB[3] = {5, 2, 4};
  const int KAv[3] = {13, 8, 13}, KBv[3] = {4, 4, 8};
  for (int t3 = 0; t3 < 3; ++t3) {
    int eA = etA[t3], eB = etB[t3];
    const float* CA = Cws + eA * 2176;
    const float* CB = Cws + eB * 2176;
    const float* pA = P + eA * kSLOT;   // [k*64 + b] layout
    const float* pB = P + eB * kSLOT;
    float cA = pA[1024 + b];
    float cB = pB[1024 + b];
    float v = cA * CA[2048 + tid] + cB * CB[2048 + tid];
    for (int k = 0; k < KAv[t3]; ++k) v += pA[k * 64 + b] * CA[k * 128 + tid];
    for (int k = 0; k < KBv[t3]; ++k) v += pB[k * 64 + b] * CB[k * 128 + tid];
    float cnt = (float)max(cnts[t3], 1);
    const float* bb1 = (t3 == 0) ? b_rv2t : (t3 == 1 ? b_t2rv : b_rv2r);
    const float* bb2 = (t3 == 0) ? b_r2t  : (t3 == 1 ? b_r2rv : b_t2r);
    xcat[b * 512 + t3 * 128 + tid] = v / cnt + bb1[tid] + bb2[tid];
  }
}

// ---------------------------------------------------------------------------
__global__ __launch_bounds__(256) void out_kernel(
    const float* __restrict__ xcat, const float* __restrict__ outW,
    const float* __restrict__ outb, float* __restrict__ out)
{
  int g = blockIdx.x * 256 + threadIdx.x;   // 64*512
  int r = g >> 9, c = g & 511;
  const float* xr = xcat + r * 512;
  float acc = outb[c];
  for (int k = 0; k < 512; ++k) acc += xr[k] * outW[k * 512 + c];
  out[g] = acc;
}

// ---------------------------------------------------------------------------
extern "C" void kernel_launch(void* const* d_in, const int* in_sizes, int n_in,
                              void* d_out, int out_size, void* d_ws, size_t ws_size,
                              hipStream_t stream) {
  const float* x_tile   = (const float*)d_in[0];
  const float* x_rv     = (const float*)d_in[1];
  const float* x_road   = (const float*)d_in[2];
  const float* x_player = (const float*)d_in[3];
  const float* enc_t_W  = (const float*)d_in[4];
  const float* enc_t_b  = (const float*)d_in[5];
  const float* enc_rv_W = (const float*)d_in[6];
  const float* enc_rv_b = (const float*)d_in[7];
  const float* enc_r_W  = (const float*)d_in[8];
  const float* enc_r_b  = (const float*)d_in[9];
  const float* W[6]; const float* As[6]; const float* Ad[6]; const float* Bb[6];
  for (int et = 0; et < 6; ++et) {
    W[et]  = (const float*)d_in[10 + 4 * et];
    As[et] = (const float*)d_in[11 + 4 * et];
    Ad[et] = (const float*)d_in[12 + 4 * et];
    Bb[et] = (const float*)d_in[13 + 4 * et];
  }
  const float* fc1W = (const float*)d_in[34];
  const float* fc1b = (const float*)d_in[35];
  const float* fc2W = (const float*)d_in[36];
  const float* fc2b = (const float*)d_in[37];
  const float* outW = (const float*)d_in[38];
  const float* outb = (const float*)d_in[39];
  const int* esrc[6]; const int* edst[6];
  for (int et = 0; et < 6; ++et) {
    esrc[et] = (const int*)d_in[40 + 2 * et];
    edst[et] = (const int*)d_in[41 + 2 * et];
  }
  const int* batch_t  = (const int*)d_in[52];
  const int* batch_rv = (const int*)d_in[53];
  const int* batch_r  = (const int*)d_in[54];

  float* wsF = (float*)d_ws;
  float* Cws  = wsF + OFF_C;
  float* vsw  = wsF + OFF_VS;
  float* vdw  = wsF + OFF_VD;
  float* P    = wsF + OFF_P;
  float* xcat = wsF + OFF_XCAT;
  uint4* SRVq = (uint4*)(wsF + OFF_SRV);
  uint4* STq  = (uint4*)(wsF + OFF_ST);
  uint4* SRq  = (uint4*)(wsF + OFF_SR);
  float* LDDf = wsF + OFF_LDD;
  float2* LDD2 = (float2*)(wsF + OFF_LDD);
  float* P8   = wsF + OFF_P8;
  float* out  = (float*)d_out;

  precompute_kernel<<<6, 256, 0, stream>>>(
      enc_t_W, enc_t_b, enc_rv_W, enc_rv_b, enc_r_W, enc_r_b,
      W[0], As[0], Ad[0], W[1], As[1], Ad[1], W[2], As[2], Ad[2],
      W[3], As[3], Ad[3], W[4], As[4], Ad[4], W[5], As[5], Ad[5],
      Cws, vsw, vdw, P8);

  prep_kernel<<<(kNT + kNRV + kNR + 255) / 256, 256, 0, stream>>>(
      x_tile, x_rv, x_road, batch_t, batch_rv, batch_r, vsw, vdw,
      SRVq, STq, SRq, LDDf);

  edgeA_kernel<<<6 * kNBE, 256, 0, stream>>>(
      esrc[0], esrc[1], esrc[2], esrc[3], esrc[4], esrc[5],
      edst[0], edst[1], edst[2], edst[3], edst[4], edst[5],
      (const unsigned*)SRVq, (const unsigned*)STq, (const unsigned*)SRq, LDDf);

  edgeB_kernel<<<6 * kNBE, 256, 0, stream>>>(
      esrc[0], esrc[1], esrc[2], esrc[3], esrc[4], esrc[5],
      edst[0], edst[1], edst[2], edst[3], edst[4], edst[5],
      SRVq, STq, SRq, LDD2, P8);

  reduceP8_kernel<<<(kPSZ + 255) / 256, 256, 0, stream>>>(P8, P);

  finalize_kernel<<<64, 128, 0, stream>>>(
      batch_t, batch_rv, batch_r, x_player,
      fc1W, fc1b, fc2W, fc2b,
      Bb[0], Bb[5], Bb[1], Bb[2], Bb[3], Bb[4],
      Cws, P, xcat);

  out_kernel<<<128, 256, 0, stream>>>(xcat, outW, outb, out);

  (void)in_sizes; (void)n_in; (void)out_size; (void)ws_size;
}